// Round 7
// baseline (159.372 us; speedup 1.0000x reference)
//
#include <hip/hip_runtime.h>
#include <stdint.h>

#define N_UNITS   400
#define N_NEIGHB  64
#define C         3
#define S         2
#define T         10      // C + C*S + E, E=1
#define NSLICE    256     // kA blocks / PA slabs
#define HW_       (N_NEIGHB * N_UNITS / 2)   // 12800 packed words (4 u8 fields each)
#define NE_TOT    (N_NEIGHB * N_UNITS)       // 25600 (nb,u) entries
#define RGROUPS   8
#define SLAB_PER_G (NSLICE / RGROUPS)        // 32
#define BS        256
#define BSA       1024                        // kA block size
#define MBLK      512                         // max k_main blocks (PD slabs)
#define EHW       (N_UNITS * 16)              // 6400 u8x4-packed explore words

// ---------- JAX Threefry-2x32, key = (0, 1) (jax.random.key(1)) ----------
__device__ __forceinline__ uint32_t rotl32(uint32_t x, int d) {
    return (x << d) | (x >> (32 - d));
}

__device__ __forceinline__ void threefry_key01(uint32_t x0, uint32_t x1,
                                               uint32_t& o0, uint32_t& o1) {
    const uint32_t ks0 = 0u;
    const uint32_t ks1 = 1u;
    const uint32_t ks2 = 0x1BD11BDBu;  // 0x1BD11BDA ^ 0 ^ 1
    x0 += ks0; x1 += ks1;
#define TF_RND(r) { x0 += x1; x1 = rotl32(x1, r); x1 ^= x0; }
    TF_RND(13) TF_RND(15) TF_RND(26) TF_RND(6)
    x0 += ks1; x1 += ks2 + 1u;
    TF_RND(17) TF_RND(29) TF_RND(16) TF_RND(24)
    x0 += ks2; x1 += ks0 + 2u;
    TF_RND(13) TF_RND(15) TF_RND(26) TF_RND(6)
    x0 += ks0; x1 += ks1 + 3u;
    TF_RND(17) TF_RND(29) TF_RND(16) TF_RND(24)
    x0 += ks1; x1 += ks2 + 4u;
    TF_RND(13) TF_RND(15) TF_RND(26) TF_RND(6)
    x0 += ks2; x1 += ks0 + 5u;
#undef TF_RND
    o0 = x0; o1 = x1;
}

// jax_threefry_partitionable=True (default since jax 0.4.36):
// bits[i] = x0 ^ x1 of threefry2x32(key, (i >> 32, i & 0xffffffff)).
__device__ __forceinline__ int explore_index(int i, int ne) {
    uint32_t o0, o1;
    threefry_key01(0u, (uint32_t)i, o0, o1);
    uint32_t bits = o0 ^ o1;
    float u = __uint_as_float((bits >> 9) | 0x3F800000u) - 1.0f;
    int t = (int)floorf(u * (float)ne);
    return min(t, ne - 1);
}

// ---------- kA: single-pass full-64-nb partial histograms (u8 fields) -----
// entry e = nb*400+u; word = e>>1; lo/hi 16b half per e; within a half:
// bits 0-7 = h0 (top0 count), bits 8-15 = h12 (top1+top2 count).
// Per-slab counts are tiny (lambda ~0.3), so u8 cannot overflow.
__global__ void k_histA(const int* __restrict__ top,
                        const int* __restrict__ nbid,
                        uint32_t* __restrict__ PA, int n, int chunk) {
    __shared__ uint32_t hist[HW_];
    for (int k = threadIdx.x; k < HW_; k += blockDim.x) hist[k] = 0u;
    __syncthreads();
    int lo = blockIdx.x * chunk, hi = min(n, lo + chunk);
    const int4* top4 = (const int4*)top;
#define PROC(nb, t0, t1, t2) { \
    int b_ = (nb) * N_UNITS; \
    int e0 = b_ + (t0), e1 = b_ + (t1), e2 = b_ + (t2); \
    atomicAdd(&hist[e0 >> 1], 1u << ((e0 & 1) * 16)); \
    atomicAdd(&hist[e1 >> 1], 0x100u << ((e1 & 1) * 16)); \
    atomicAdd(&hist[e2 >> 1], 0x100u << ((e2 & 1) * 16)); }
    for (int i0 = lo + threadIdx.x * 4; i0 < hi; i0 += blockDim.x * 4) {
        if (i0 + 4 <= hi) {
            int4 nb4 = *(const int4*)(nbid + i0);
            int j = (i0 * 3) >> 2;
            int4 ta = top4[j], tb = top4[j + 1], tc = top4[j + 2];
            PROC(nb4.x, ta.x, ta.y, ta.z)
            PROC(nb4.y, ta.w, tb.x, tb.y)
            PROC(nb4.z, tb.z, tb.w, tc.x)
            PROC(nb4.w, tc.y, tc.z, tc.w)
        } else {
            for (int i = i0; i < hi; ++i)
                PROC(nbid[i], top[3 * i], top[3 * i + 1], top[3 * i + 2])
        }
    }
#undef PROC
    __syncthreads();
    uint32_t* Pb = PA + (size_t)blockIdx.x * HW_;
    for (int k = threadIdx.x; k < HW_; k += blockDim.x) Pb[k] = hist[k];
}

// ---------- kR: wide reduce of PA slabs into 8 packed partials ------------
// 400 blocks: full-chip spread of the 13.1 MB PA read (do NOT fuse into kB:
// 64-block version is latency-bound on 25% of CUs — round-4 regression).
__global__ void k_reduceA(const uint32_t* __restrict__ PA,
                          uint32_t* __restrict__ R8) {
    int idx = blockIdx.x * blockDim.x + threadIdx.x;   // 0 .. 8*HW_-1
    int w = idx % HW_;
    int g = idx / HW_;
    uint32_t h0a = 0, h12a = 0, h0b = 0, h12b = 0;
    const uint32_t* p = PA + (size_t)g * SLAB_PER_G * HW_ + w;
#pragma unroll 8
    for (int s = 0; s < SLAB_PER_G; ++s) {
        uint32_t v = p[(size_t)s * HW_];
        h0a  += v & 0xFFu;
        h12a += (v >> 8) & 0xFFu;
        h0b  += (v >> 16) & 0xFFu;
        h12b += v >> 24;
    }
    uint32_t* o = R8 + (size_t)g * NE_TOT;
    o[2 * w]     = h0a | (h12a << 16);
    o[2 * w + 1] = h0b | (h12b << 16);
}

// ---------- kB: ballot-scan tables + base counts (2 barriers) -------------
__global__ void k_tables_base(const uint32_t* __restrict__ R8,
                              const int* __restrict__ usn,
                              int* __restrict__ wtbl,
                              int* __restrict__ wne,
                              float* __restrict__ out_counts) {
    __shared__ int s_c[N_UNITS];
    __shared__ int wsum[8];
    int b = blockIdx.x;          // neighborhood id
    int u = threadIdx.x;         // 512 threads = 8 waves
    int h0 = 0, h3 = 0;
    if (u < N_UNITS) {
        int e = b * N_UNITS + u;
        // packed u16-field add: per-field totals << 65536, no cross-carry
        uint32_t tot = 0;
#pragma unroll
        for (int g = 0; g < RGROUPS; ++g) tot += R8[g * NE_TOT + e];
        h0 = (int)(tot & 0xFFFFu);
        h3 = h0 + (int)(tot >> 16);
        s_c[u] = h3;              // top0 + top1/top2 contributions
    }
    bool p = (u < N_UNITS) && (h0 > 0);
    unsigned long long m = __ballot(p);
    int lane = u & 63, wid = u >> 6;
    if (lane == 0) wsum[wid] = __popcll(m);
    int lp = __popcll(m & ((1ull << lane) - 1ull));
    __syncthreads();              // covers s_c and wsum
    int off = 0;
    for (int w2 = 0; w2 < wid; ++w2) off += wsum[w2];
    if (p) wtbl[b * N_UNITS + off + lp] = u;   // ascending unit order kept
    if (u == 0) {
        int tot = 0;
        for (int w2 = 0; w2 < 8; ++w2) tot += wsum[w2];
        wne[b] = tot;
    }
    if (u < N_UNITS && h3 > 0) {
        int2 nbr = ((const int2*)usn)[u];
        atomicAdd(&s_c[nbr.x], h3);
        atomicAdd(&s_c[nbr.y], h3);
    }
    __syncthreads();
    if (u < N_UNITS)
        out_counts[u * N_NEIGHB + b] = (float)s_c[u];
}

// ---------- k_main: barrier-free quad-streaming candidates + scores -------
// Each thread owns 4 consecutive spikes (one quad): reads 1 int4 of nbid and
// 3 int4 of top, computes all 4 spikes' candidates in registers, writes each
// output array as 10 aligned float4 (quad span = 160 B, 16-aligned).
// No LDS staging of cand, no inner barriers; LDS ~30.7 KB -> 4-5 blocks/CU.
__global__ __launch_bounds__(BS, 4)
void k_main(const float* __restrict__ logliks,
            const int* __restrict__ top,
            const int* __restrict__ usn,
            const int* __restrict__ nbid,
            const int* __restrict__ wtbl,
            const int* __restrict__ wne,
            uint32_t* __restrict__ PD,
            float* __restrict__ out_cand,
            float* __restrict__ out_scores,
            int n, int qchunk) {
    __shared__ uint32_t hist[EHW];                       // 25.6 KB
    __shared__ int   s_usn[N_UNITS * S];                 // 3.2 KB
    __shared__ float s_ll[N_UNITS];                      // 1.6 KB
    __shared__ int   s_ne[N_NEIGHB];                     // 0.25 KB
    int tid = threadIdx.x;
    for (int k = tid; k < EHW; k += BS) hist[k] = 0u;
    for (int k = tid; k < N_UNITS * S; k += BS) s_usn[k] = usn[k];
    for (int k = tid; k < N_UNITS; k += BS)     s_ll[k]  = logliks[k];
    for (int k = tid; k < N_NEIGHB; k += BS)    s_ne[k]  = wne[k];
    __syncthreads();

    // per-spike candidate build + dup-erase; vv gets the T final values
    auto do_spike = [&](int i, int nb, int t0v, int t1v, int t2v, int* vv) {
        int cand[T];
        cand[0] = t0v; cand[1] = t1v; cand[2] = t2v;
#pragma unroll
        for (int c = 0; c < C; ++c) {
            cand[C + 2 * c]     = s_usn[cand[c] * 2 + 0];
            cand[C + 2 * c + 1] = s_usn[cand[c] * 2 + 1];
        }
        int ne = s_ne[nb];
        if (ne > 0) {
            int t = explore_index(i, ne);
            int ex = wtbl[nb * N_UNITS + t];
            cand[T - 1] = ex;
            // explore tail-count (pre-dup), u8 field per nb
            atomicAdd(&hist[ex * 16 + (nb >> 2)], 1u << ((nb & 3) * 8));
        } else {
            cand[T - 1] = -1;
        }
#pragma unroll
        for (int jj = 0; jj < T; ++jj) {
            bool dup = false;
#pragma unroll
            for (int k = 0; k < jj; ++k) dup |= (cand[k] == cand[jj]);
            vv[jj] = dup ? -1 : cand[jj];
        }
    };

    int nq = (n + 3) >> 2;
    int qlo = blockIdx.x * qchunk, qhi = min(nq, qlo + qchunk);
    const int4* top4 = (const int4*)top;
    const int4* nb4p = (const int4*)nbid;

    for (int q = qlo + tid; q < qhi; q += BS) {
        int i0 = q << 2;
        if (i0 + 4 <= n) {
            int4 nbq = nb4p[q];
            int4 a = top4[3 * q], b = top4[3 * q + 1], c = top4[3 * q + 2];
            int vi[4 * T];                       // all indices static
            do_spike(i0 + 0, nbq.x, a.x, a.y, a.z, vi);
            do_spike(i0 + 1, nbq.y, a.w, b.x, b.y, vi + T);
            do_spike(i0 + 2, nbq.z, b.z, b.w, c.x, vi + 2 * T);
            do_spike(i0 + 3, nbq.w, c.y, c.z, c.w, vi + 3 * T);
            float4* oc = (float4*)(out_cand   + (size_t)i0 * T);
            float4* os = (float4*)(out_scores + (size_t)i0 * T);
#pragma unroll
            for (int w = 0; w < T; ++w) {        // 10 float4 per array
                int v0 = vi[4 * w], v1 = vi[4 * w + 1];
                int v2 = vi[4 * w + 2], v3 = vi[4 * w + 3];
                oc[w] = make_float4((float)v0, (float)v1, (float)v2, (float)v3);
                os[w] = make_float4(v0 >= 0 ? s_ll[v0] : 0.0f,
                                    v1 >= 0 ? s_ll[v1] : 0.0f,
                                    v2 >= 0 ? s_ll[v2] : 0.0f,
                                    v3 >= 0 ? s_ll[v3] : 0.0f);
            }
        } else {
            for (int j = 0; j < 4; ++j) {        // last (partial) quad only
                int i = i0 + j;
                if (i >= n) break;
                int vv[T];
                do_spike(i, nbid[i], top[3 * i], top[3 * i + 1], top[3 * i + 2], vv);
                for (int jj = 0; jj < T; ++jj) {
                    int v = vv[jj];
                    out_cand[(size_t)i * T + jj]   = (float)v;
                    out_scores[(size_t)i * T + jj] = (v >= 0) ? s_ll[v] : 0.0f;
                }
            }
        }
    }
    __syncthreads();        // all hist atomics complete
    uint32_t* Pb = PD + (size_t)blockIdx.x * EHW;
    for (int k = tid; k < EHW; k += BS) Pb[k] = hist[k];
}

// ---------- kF: reduce u8-packed explore partials into out_counts ---------
// 200 blocks: 32 words x 8 slab-groups each.
__global__ void k_finalE(const uint32_t* __restrict__ PD,
                         float* __restrict__ out_counts, int nslab) {
    __shared__ uint32_t red_e[256], red_o[256];
    int tid = threadIdx.x;
    int wl = tid & 31, g = tid >> 5;            // 8 slab groups
    int w = blockIdx.x * 32 + wl;               // word index in [0, EHW)
    int per = (nslab + 7) >> 3;
    int s0 = g * per, s1 = min(nslab, s0 + per);
    uint32_t acc_e = 0, acc_o = 0;              // u16 lanes: fields 0/2, 1/3
    for (int s = s0; s < s1; ++s) {
        uint32_t v = PD[(size_t)s * EHW + w];
        acc_e += v & 0x00FF00FFu;
        acc_o += (v >> 8) & 0x00FF00FFu;
    }
    red_e[tid] = acc_e;
    red_o[tid] = acc_o;
    __syncthreads();
    if (g == 0) {
        // unpack BEFORE combining groups (avoid u16-lane carry)
        uint32_t c0 = 0, c1 = 0, c2 = 0, c3 = 0;
#pragma unroll
        for (int k = 0; k < 8; ++k) {
            uint32_t e = red_e[wl + 32 * k], o = red_o[wl + 32 * k];
            c0 += e & 0xFFFFu;  c2 += e >> 16;
            c1 += o & 0xFFFFu;  c3 += o >> 16;
        }
        int u = w >> 4, nb4 = (w & 15) * 4;
        float4* p = (float4*)(out_counts + u * N_NEIGHB + nb4);
        float4 v = *p;
        v.x += (float)c0;
        v.y += (float)c1;
        v.z += (float)c2;
        v.w += (float)c3;
        *p = v;
    }
}

extern "C" void kernel_launch(void* const* d_in, const int* in_sizes, int n_in,
                              void* d_out, int out_size, void* d_ws, size_t ws_size,
                              hipStream_t stream) {
    const float* logliks = (const float*)d_in[0];
    const int*   top     = (const int*)d_in[1];
    const int*   usn     = (const int*)d_in[2];
    const int*   nbid    = (const int*)d_in[3];

    int n = in_sizes[3];                                 // N_SPIKES
    int chunkA = ((n + NSLICE - 1) / NSLICE + 3) & ~3;   // mult of 4 (int4 path)
    int nq = (n + 3) >> 2;                               // quads
    int qchunk = (nq + MBLK - 1) / MBLK;                 // quads per block
    int mb = (nq + qchunk - 1) / qchunk;                 // <= 512 k_main blocks

    float* out        = (float*)d_out;
    float* out_cand   = out;
    float* out_counts = out + (size_t)n * T;
    float* out_scores = out_counts + (size_t)N_UNITS * N_NEIGHB;

    // Scratch in d_ws (~27.1 MB used):
    int*      wtbl = (int*)d_ws;                         // [64][400]
    int*      wne  = wtbl + N_NEIGHB * N_UNITS;          // [64]
    uint32_t* R8   = (uint32_t*)(wne + 64);              // 8*25600 = 819.2 KB
    uint32_t* PA   = R8 + (size_t)RGROUPS * NE_TOT;      // 256*12800 = 13.1 MB
    uint32_t* PD   = PA + (size_t)NSLICE * HW_;          // <=512*6400 = 13.1 MB

    k_histA      <<<NSLICE, BSA, 0, stream>>>(top, nbid, PA, n, chunkA);
    k_reduceA    <<<(RGROUPS * HW_) / BS, BS, 0, stream>>>(PA, R8);
    k_tables_base<<<N_NEIGHB, 512, 0, stream>>>(R8, usn, wtbl, wne, out_counts);
    k_main       <<<mb, BS, 0, stream>>>(logliks, top, usn, nbid, wtbl, wne,
                                         PD, out_cand, out_scores, n, qchunk);
    k_finalE     <<<EHW / 32, BS, 0, stream>>>(PD, out_counts, mb);
}

// Round 9
// 136.011 us; speedup vs baseline: 1.1718x; 1.1718x over previous
//
#include <hip/hip_runtime.h>
#include <stdint.h>

#define N_UNITS   400
#define N_NEIGHB  64
#define C         3
#define S         2
#define T         10      // C + C*S + E, E=1
#define NSLICE    256     // kA blocks / PA slabs
#define HW_       (N_NEIGHB * N_UNITS / 2)   // 12800 packed words (4 u8 fields each)
#define NE_TOT    (N_NEIGHB * N_UNITS)       // 25600 (nb,u) entries
#define RGROUPS   8
#define SLAB_PER_G (NSLICE / RGROUPS)        // 32
#define BS        256
#define BSA       1024                        // kA block size
#define MBLK      512                         // max k_main blocks (PD slabs)
#define EHW       (N_UNITS * 16)              // 6400 u8x4-packed explore words

// ---------- JAX Threefry-2x32, key = (0, 1) (jax.random.key(1)) ----------
__device__ __forceinline__ uint32_t rotl32(uint32_t x, int d) {
    return (x << d) | (x >> (32 - d));
}

__device__ __forceinline__ void threefry_key01(uint32_t x0, uint32_t x1,
                                               uint32_t& o0, uint32_t& o1) {
    const uint32_t ks0 = 0u;
    const uint32_t ks1 = 1u;
    const uint32_t ks2 = 0x1BD11BDBu;  // 0x1BD11BDA ^ 0 ^ 1
    x0 += ks0; x1 += ks1;
#define TF_RND(r) { x0 += x1; x1 = rotl32(x1, r); x1 ^= x0; }
    TF_RND(13) TF_RND(15) TF_RND(26) TF_RND(6)
    x0 += ks1; x1 += ks2 + 1u;
    TF_RND(17) TF_RND(29) TF_RND(16) TF_RND(24)
    x0 += ks2; x1 += ks0 + 2u;
    TF_RND(13) TF_RND(15) TF_RND(26) TF_RND(6)
    x0 += ks0; x1 += ks1 + 3u;
    TF_RND(17) TF_RND(29) TF_RND(16) TF_RND(24)
    x0 += ks1; x1 += ks2 + 4u;
    TF_RND(13) TF_RND(15) TF_RND(26) TF_RND(6)
    x0 += ks2; x1 += ks0 + 5u;
#undef TF_RND
    o0 = x0; o1 = x1;
}

// jax_threefry_partitionable=True (default since jax 0.4.36):
// bits[i] = x0 ^ x1 of threefry2x32(key, (i >> 32, i & 0xffffffff)).
__device__ __forceinline__ int explore_index(int i, int ne) {
    uint32_t o0, o1;
    threefry_key01(0u, (uint32_t)i, o0, o1);
    uint32_t bits = o0 ^ o1;
    float u = __uint_as_float((bits >> 9) | 0x3F800000u) - 1.0f;
    int t = (int)floorf(u * (float)ne);
    return min(t, ne - 1);
}

// ---------- kA: single-pass full-64-nb partial histograms (u8 fields) -----
// entry e = nb*400+u; word = e>>1; lo/hi 16b half per e; within a half:
// bits 0-7 = h0 (top0 count), bits 8-15 = h12 (top1+top2 count).
// Per-slab counts are tiny (lambda ~0.3), so u8 cannot overflow.
__global__ void k_histA(const int* __restrict__ top,
                        const int* __restrict__ nbid,
                        uint32_t* __restrict__ PA, int n, int chunk) {
    __shared__ uint32_t hist[HW_];
    for (int k = threadIdx.x; k < HW_; k += blockDim.x) hist[k] = 0u;
    __syncthreads();
    int lo = blockIdx.x * chunk, hi = min(n, lo + chunk);
    const int4* top4 = (const int4*)top;
#define PROC(nb, t0, t1, t2) { \
    int b_ = (nb) * N_UNITS; \
    int e0 = b_ + (t0), e1 = b_ + (t1), e2 = b_ + (t2); \
    atomicAdd(&hist[e0 >> 1], 1u << ((e0 & 1) * 16)); \
    atomicAdd(&hist[e1 >> 1], 0x100u << ((e1 & 1) * 16)); \
    atomicAdd(&hist[e2 >> 1], 0x100u << ((e2 & 1) * 16)); }
    for (int i0 = lo + threadIdx.x * 4; i0 < hi; i0 += blockDim.x * 4) {
        if (i0 + 4 <= hi) {
            int4 nb4 = *(const int4*)(nbid + i0);
            int j = (i0 * 3) >> 2;
            int4 ta = top4[j], tb = top4[j + 1], tc = top4[j + 2];
            PROC(nb4.x, ta.x, ta.y, ta.z)
            PROC(nb4.y, ta.w, tb.x, tb.y)
            PROC(nb4.z, tb.z, tb.w, tc.x)
            PROC(nb4.w, tc.y, tc.z, tc.w)
        } else {
            for (int i = i0; i < hi; ++i)
                PROC(nbid[i], top[3 * i], top[3 * i + 1], top[3 * i + 2])
        }
    }
#undef PROC
    __syncthreads();
    uint32_t* Pb = PA + (size_t)blockIdx.x * HW_;
    for (int k = threadIdx.x; k < HW_; k += blockDim.x) Pb[k] = hist[k];
}

// ---------- kR: wide reduce of PA slabs into 8 packed partials ------------
// 400 blocks: full-chip spread of the 13.1 MB PA read (do NOT fuse into kB:
// 64-block version is latency-bound on 25% of CUs — round-4 regression).
__global__ void k_reduceA(const uint32_t* __restrict__ PA,
                          uint32_t* __restrict__ R8) {
    int idx = blockIdx.x * blockDim.x + threadIdx.x;   // 0 .. 8*HW_-1
    int w = idx % HW_;
    int g = idx / HW_;
    uint32_t h0a = 0, h12a = 0, h0b = 0, h12b = 0;
    const uint32_t* p = PA + (size_t)g * SLAB_PER_G * HW_ + w;
#pragma unroll 8
    for (int s = 0; s < SLAB_PER_G; ++s) {
        uint32_t v = p[(size_t)s * HW_];
        h0a  += v & 0xFFu;
        h12a += (v >> 8) & 0xFFu;
        h0b  += (v >> 16) & 0xFFu;
        h12b += v >> 24;
    }
    uint32_t* o = R8 + (size_t)g * NE_TOT;
    o[2 * w]     = h0a | (h12a << 16);
    o[2 * w + 1] = h0b | (h12b << 16);
}

// ---------- kB: ballot-scan tables + base counts (2 barriers) -------------
__global__ void k_tables_base(const uint32_t* __restrict__ R8,
                              const int* __restrict__ usn,
                              int* __restrict__ wtbl,
                              int* __restrict__ wne,
                              float* __restrict__ out_counts) {
    __shared__ int s_c[N_UNITS];
    __shared__ int wsum[8];
    int b = blockIdx.x;          // neighborhood id
    int u = threadIdx.x;         // 512 threads = 8 waves
    int h0 = 0, h3 = 0;
    if (u < N_UNITS) {
        int e = b * N_UNITS + u;
        // packed u16-field add: per-field totals << 65536, no cross-carry
        uint32_t tot = 0;
#pragma unroll
        for (int g = 0; g < RGROUPS; ++g) tot += R8[g * NE_TOT + e];
        h0 = (int)(tot & 0xFFFFu);
        h3 = h0 + (int)(tot >> 16);
        s_c[u] = h3;              // top0 + top1/top2 contributions
    }
    bool p = (u < N_UNITS) && (h0 > 0);
    unsigned long long m = __ballot(p);
    int lane = u & 63, wid = u >> 6;
    if (lane == 0) wsum[wid] = __popcll(m);
    int lp = __popcll(m & ((1ull << lane) - 1ull));
    __syncthreads();              // covers s_c and wsum
    int off = 0;
    for (int w2 = 0; w2 < wid; ++w2) off += wsum[w2];
    if (p) wtbl[b * N_UNITS + off + lp] = u;   // ascending unit order kept
    if (u == 0) {
        int tot = 0;
        for (int w2 = 0; w2 < 8; ++w2) tot += wsum[w2];
        wne[b] = tot;
    }
    if (u < N_UNITS && h3 > 0) {
        int2 nbr = ((const int2*)usn)[u];
        atomicAdd(&s_c[nbr.x], h3);
        atomicAdd(&s_c[nbr.y], h3);
    }
    __syncthreads();
    if (u < N_UNITS)
        out_counts[u * N_NEIGHB + b] = (float)s_c[u];
}

// ---------- k_main: barrier-free streaming + wave-local LDS transpose -----
// Each lane computes ONE spike's 10 candidates, packs them as 5 u32 (u16
// fields) into a per-wave 320-word LDS tile (stride-5 -> conflict-free).
// After lgkmcnt(0) (wave-lockstep: no block barrier needed), the wave
// re-reads transposed and stores fully-coalesced float4/float2 runs
// (lane-contiguous -> no partial-line write amplification; round-7 lesson:
// per-lane 160B spans caused 2.1x HBM write blowup).
// Element map: u16 elem e in [0,640) lives in word e/2 (half e&1);
// read round k in {0,1}: lane L reads uint2 index L + 64*k = words
// {128k+2L, 128k+2L+1} = elems 256k+4L..+3 -> wo = 256k + 4L.  (Round-8 bug:
// 128*k indexed words 256..383 for k=1 — OOB into the next wave's tile.)
// Round 2: word 256+L = elems 512+2L, 513+2L -> wo = 512 + 2L.
// LDS ~35.8 KB -> 4 blocks/CU; zero inner barriers.
__global__ __launch_bounds__(BS, 4)
void k_main(const float* __restrict__ logliks,
            const int* __restrict__ top,
            const int* __restrict__ usn,
            const int* __restrict__ nbid,
            const int* __restrict__ wtbl,
            const int* __restrict__ wne,
            uint32_t* __restrict__ PD,
            float* __restrict__ out_cand,
            float* __restrict__ out_scores,
            int n, int chunk) {
    __shared__ uint32_t hist[EHW];                       // 25.6 KB
    __shared__ int   s_usn[N_UNITS * S];                 // 3.2 KB
    __shared__ float s_ll[N_UNITS];                      // 1.6 KB
    __shared__ int   s_ne[N_NEIGHB];                     // 0.25 KB
    __shared__ uint32_t xbuf[BS / 64][320];              // 5.12 KB transpose tiles
    int tid = threadIdx.x;
    for (int k = tid; k < EHW; k += BS) hist[k] = 0u;
    for (int k = tid; k < N_UNITS * S; k += BS) s_usn[k] = usn[k];
    for (int k = tid; k < N_UNITS; k += BS)     s_ll[k]  = logliks[k];
    for (int k = tid; k < N_NEIGHB; k += BS)    s_ne[k]  = wne[k];
    __syncthreads();

    int lane = tid & 63, wid = tid >> 6;
    uint32_t* xb = xbuf[wid];

    // per-spike candidate build + dup-erase; vv gets the T final values
    auto do_spike = [&](int i, int nb, int t0v, int t1v, int t2v, int* vv) {
        int cand[T];
        cand[0] = t0v; cand[1] = t1v; cand[2] = t2v;
#pragma unroll
        for (int c = 0; c < C; ++c) {
            cand[C + 2 * c]     = s_usn[cand[c] * 2 + 0];
            cand[C + 2 * c + 1] = s_usn[cand[c] * 2 + 1];
        }
        int ne = s_ne[nb];
        if (ne > 0) {
            int t = explore_index(i, ne);
            int ex = wtbl[nb * N_UNITS + t];
            cand[T - 1] = ex;
            // explore tail-count (pre-dup), u8 field per nb
            atomicAdd(&hist[ex * 16 + (nb >> 2)], 1u << ((nb & 3) * 8));
        } else {
            cand[T - 1] = -1;
        }
#pragma unroll
        for (int jj = 0; jj < T; ++jj) {
            bool dup = false;
#pragma unroll
            for (int k = 0; k < jj; ++k) dup |= (cand[k] == cand[jj]);
            vv[jj] = dup ? -1 : cand[jj];
        }
    };

    int lo = blockIdx.x * chunk, hi = min(n, lo + chunk);
    for (int wbase = lo + wid * 64; wbase < hi; wbase += BS) {
        if (wbase + 64 <= hi) {
            int i = wbase + lane;
            int nb = nbid[i];                    // wave: 256B contiguous
            const int* tp = top + 3 * (size_t)i; // wave: 768B contiguous
            int vv[T];
            do_spike(i, nb, tp[0], tp[1], tp[2], vv);
            // pack 10 u16 -> 5 u32; LDS stride-5 across lanes = conflict-free
#pragma unroll
            for (int k = 0; k < T / 2; ++k)
                xb[lane * 5 + k] = (uint32_t)(unsigned short)vv[2 * k]
                                 | ((uint32_t)(unsigned short)vv[2 * k + 1] << 16);
            // intra-wave cross-lane visibility: drain LDS writes (lockstep wave)
            asm volatile("s_waitcnt lgkmcnt(0)" ::: "memory");
            __builtin_amdgcn_sched_barrier(0);

            float* ocw = out_cand   + (size_t)wbase * T;
            float* osw = out_scores + (size_t)wbase * T;
            const uint2* xb2 = (const uint2*)xb;
            // rounds 0/1: elems [0,512): lane L round k -> elems 256k+4L..+3
#pragma unroll
            for (int k = 0; k < 2; ++k) {
                uint2 wv = xb2[lane + 64 * k];   // words 128k+2L, 128k+2L+1
                int v0 = (short)(wv.x & 0xFFFFu), v1 = (short)(wv.x >> 16);
                int v2 = (short)(wv.y & 0xFFFFu), v3 = (short)(wv.y >> 16);
                int wo = 4 * lane + 256 * k;
                *(float4*)(ocw + wo) =
                    make_float4((float)v0, (float)v1, (float)v2, (float)v3);
                *(float4*)(osw + wo) =
                    make_float4(v0 >= 0 ? s_ll[v0] : 0.0f,
                                v1 >= 0 ? s_ll[v1] : 0.0f,
                                v2 >= 0 ? s_ll[v2] : 0.0f,
                                v3 >= 0 ? s_ll[v3] : 0.0f);
            }
            // round 2 (partial): elems [512,640): word 256+L
            {
                uint32_t wv = xb[256 + lane];
                int v0 = (short)(wv & 0xFFFFu), v1 = (short)(wv >> 16);
                int wo = 512 + 2 * lane;
                *(float2*)(ocw + wo) = make_float2((float)v0, (float)v1);
                *(float2*)(osw + wo) =
                    make_float2(v0 >= 0 ? s_ll[v0] : 0.0f,
                                v1 >= 0 ? s_ll[v1] : 0.0f);
            }
            // stores consumed the LDS reads (compiler-waited); next-iter
            // ds_writes issue after, and the per-wave LDS pipe is in-order.
        } else {
            int i = wbase + lane;                // partial tail round (<64)
            if (i < hi) {
                int vv[T];
                do_spike(i, nbid[i], top[3 * i], top[3 * i + 1],
                         top[3 * i + 2], vv);
                for (int jj = 0; jj < T; ++jj) {
                    int v = vv[jj];
                    out_cand[(size_t)i * T + jj]   = (float)v;
                    out_scores[(size_t)i * T + jj] = (v >= 0) ? s_ll[v] : 0.0f;
                }
            }
        }
    }
    __syncthreads();        // all hist atomics complete
    uint32_t* Pb = PD + (size_t)blockIdx.x * EHW;
    for (int k = tid; k < EHW; k += BS) Pb[k] = hist[k];
}

// ---------- kF: reduce u8-packed explore partials into out_counts ---------
// 200 blocks: 32 words x 8 slab-groups each.
__global__ void k_finalE(const uint32_t* __restrict__ PD,
                         float* __restrict__ out_counts, int nslab) {
    __shared__ uint32_t red_e[256], red_o[256];
    int tid = threadIdx.x;
    int wl = tid & 31, g = tid >> 5;            // 8 slab groups
    int w = blockIdx.x * 32 + wl;               // word index in [0, EHW)
    int per = (nslab + 7) >> 3;
    int s0 = g * per, s1 = min(nslab, s0 + per);
    uint32_t acc_e = 0, acc_o = 0;              // u16 lanes: fields 0/2, 1/3
    for (int s = s0; s < s1; ++s) {
        uint32_t v = PD[(size_t)s * EHW + w];
        acc_e += v & 0x00FF00FFu;
        acc_o += (v >> 8) & 0x00FF00FFu;
    }
    red_e[tid] = acc_e;
    red_o[tid] = acc_o;
    __syncthreads();
    if (g == 0) {
        // unpack BEFORE combining groups (avoid u16-lane carry)
        uint32_t c0 = 0, c1 = 0, c2 = 0, c3 = 0;
#pragma unroll
        for (int k = 0; k < 8; ++k) {
            uint32_t e = red_e[wl + 32 * k], o = red_o[wl + 32 * k];
            c0 += e & 0xFFFFu;  c2 += e >> 16;
            c1 += o & 0xFFFFu;  c3 += o >> 16;
        }
        int u = w >> 4, nb4 = (w & 15) * 4;
        float4* p = (float4*)(out_counts + u * N_NEIGHB + nb4);
        float4 v = *p;
        v.x += (float)c0;
        v.y += (float)c1;
        v.z += (float)c2;
        v.w += (float)c3;
        *p = v;
    }
}

extern "C" void kernel_launch(void* const* d_in, const int* in_sizes, int n_in,
                              void* d_out, int out_size, void* d_ws, size_t ws_size,
                              hipStream_t stream) {
    const float* logliks = (const float*)d_in[0];
    const int*   top     = (const int*)d_in[1];
    const int*   usn     = (const int*)d_in[2];
    const int*   nbid    = (const int*)d_in[3];

    int n = in_sizes[3];                                 // N_SPIKES
    int chunkA = ((n + NSLICE - 1) / NSLICE + 3) & ~3;   // mult of 4 (int4 path)
    // k_main chunk: multiple of 256 so every wave-round is full (n % 64 == 0)
    int chunkM = (((n + MBLK - 1) / MBLK) + 255) & ~255;
    int mb = (n + chunkM - 1) / chunkM;                  // <= 512 blocks

    float* out        = (float*)d_out;
    float* out_cand   = out;
    float* out_counts = out + (size_t)n * T;
    float* out_scores = out_counts + (size_t)N_UNITS * N_NEIGHB;

    // Scratch in d_ws (~27.1 MB used):
    int*      wtbl = (int*)d_ws;                         // [64][400]
    int*      wne  = wtbl + N_NEIGHB * N_UNITS;          // [64]
    uint32_t* R8   = (uint32_t*)(wne + 64);              // 8*25600 = 819.2 KB
    uint32_t* PA   = R8 + (size_t)RGROUPS * NE_TOT;      // 256*12800 = 13.1 MB
    uint32_t* PD   = PA + (size_t)NSLICE * HW_;          // <=512*6400 = 13.1 MB

    k_histA      <<<NSLICE, BSA, 0, stream>>>(top, nbid, PA, n, chunkA);
    k_reduceA    <<<(RGROUPS * HW_) / BS, BS, 0, stream>>>(PA, R8);
    k_tables_base<<<N_NEIGHB, 512, 0, stream>>>(R8, usn, wtbl, wne, out_counts);
    k_main       <<<mb, BS, 0, stream>>>(logliks, top, usn, nbid, wtbl, wne,
                                         PD, out_cand, out_scores, n, chunkM);
    k_finalE     <<<EHW / 32, BS, 0, stream>>>(PD, out_counts, mb);
}

// Round 10
// 131.438 us; speedup vs baseline: 1.2125x; 1.0348x over previous
//
#include <hip/hip_runtime.h>
#include <stdint.h>

#define N_UNITS   400
#define N_NEIGHB  64
#define C         3
#define S         2
#define T         10      // C + C*S + E, E=1
#define NSLICE    256     // kA blocks / PA slabs
#define HW_       (N_NEIGHB * N_UNITS / 2)   // 12800 packed words (4 u8 fields each)
#define NE_TOT    (N_NEIGHB * N_UNITS)       // 25600 (nb,u) entries
#define RGROUPS   8
#define SLAB_PER_G (NSLICE / RGROUPS)        // 32
#define BS        256
#define BSM       512                         // k_main block size (8 waves)
#define BSA       1024                        // kA block size
#define MBLK      512                         // max k_main blocks (PD slabs)
#define EHW       (N_UNITS * 16)              // 6400 u8x4-packed explore words

// ---------- JAX Threefry-2x32, key = (0, 1) (jax.random.key(1)) ----------
__device__ __forceinline__ uint32_t rotl32(uint32_t x, int d) {
    return (x << d) | (x >> (32 - d));
}

__device__ __forceinline__ void threefry_key01(uint32_t x0, uint32_t x1,
                                               uint32_t& o0, uint32_t& o1) {
    const uint32_t ks0 = 0u;
    const uint32_t ks1 = 1u;
    const uint32_t ks2 = 0x1BD11BDBu;  // 0x1BD11BDA ^ 0 ^ 1
    x0 += ks0; x1 += ks1;
#define TF_RND(r) { x0 += x1; x1 = rotl32(x1, r); x1 ^= x0; }
    TF_RND(13) TF_RND(15) TF_RND(26) TF_RND(6)
    x0 += ks1; x1 += ks2 + 1u;
    TF_RND(17) TF_RND(29) TF_RND(16) TF_RND(24)
    x0 += ks2; x1 += ks0 + 2u;
    TF_RND(13) TF_RND(15) TF_RND(26) TF_RND(6)
    x0 += ks0; x1 += ks1 + 3u;
    TF_RND(17) TF_RND(29) TF_RND(16) TF_RND(24)
    x0 += ks1; x1 += ks2 + 4u;
    TF_RND(13) TF_RND(15) TF_RND(26) TF_RND(6)
    x0 += ks2; x1 += ks0 + 5u;
#undef TF_RND
    o0 = x0; o1 = x1;
}

// jax_threefry_partitionable=True (default since jax 0.4.36):
// bits[i] = x0 ^ x1 of threefry2x32(key, (i >> 32, i & 0xffffffff)).
__device__ __forceinline__ int explore_index(int i, int ne) {
    uint32_t o0, o1;
    threefry_key01(0u, (uint32_t)i, o0, o1);
    uint32_t bits = o0 ^ o1;
    float u = __uint_as_float((bits >> 9) | 0x3F800000u) - 1.0f;
    int t = (int)floorf(u * (float)ne);
    return min(t, ne - 1);
}

// ---------- kA: single-pass full-64-nb partial histograms (u8 fields) -----
// entry e = nb*400+u; word = e>>1; lo/hi 16b half per e; within a half:
// bits 0-7 = h0 (top0 count), bits 8-15 = h12 (top1+top2 count).
// Per-slab counts are tiny (lambda ~0.3), so u8 cannot overflow.
__global__ void k_histA(const int* __restrict__ top,
                        const int* __restrict__ nbid,
                        uint32_t* __restrict__ PA, int n, int chunk) {
    __shared__ uint32_t hist[HW_];
    for (int k = threadIdx.x; k < HW_; k += blockDim.x) hist[k] = 0u;
    __syncthreads();
    int lo = blockIdx.x * chunk, hi = min(n, lo + chunk);
    const int4* top4 = (const int4*)top;
#define PROC(nb, t0, t1, t2) { \
    int b_ = (nb) * N_UNITS; \
    int e0 = b_ + (t0), e1 = b_ + (t1), e2 = b_ + (t2); \
    atomicAdd(&hist[e0 >> 1], 1u << ((e0 & 1) * 16)); \
    atomicAdd(&hist[e1 >> 1], 0x100u << ((e1 & 1) * 16)); \
    atomicAdd(&hist[e2 >> 1], 0x100u << ((e2 & 1) * 16)); }
    for (int i0 = lo + threadIdx.x * 4; i0 < hi; i0 += blockDim.x * 4) {
        if (i0 + 4 <= hi) {
            int4 nb4 = *(const int4*)(nbid + i0);
            int j = (i0 * 3) >> 2;
            int4 ta = top4[j], tb = top4[j + 1], tc = top4[j + 2];
            PROC(nb4.x, ta.x, ta.y, ta.z)
            PROC(nb4.y, ta.w, tb.x, tb.y)
            PROC(nb4.z, tb.z, tb.w, tc.x)
            PROC(nb4.w, tc.y, tc.z, tc.w)
        } else {
            for (int i = i0; i < hi; ++i)
                PROC(nbid[i], top[3 * i], top[3 * i + 1], top[3 * i + 2])
        }
    }
#undef PROC
    __syncthreads();
    uint32_t* Pb = PA + (size_t)blockIdx.x * HW_;
    for (int k = threadIdx.x; k < HW_; k += blockDim.x) Pb[k] = hist[k];
}

// ---------- kR: wide reduce of PA slabs into 8 packed partials ------------
// 400 blocks: full-chip spread of the 13.1 MB PA read (do NOT fuse into kB:
// 64-block version is latency-bound on 25% of CUs — round-4 regression).
__global__ void k_reduceA(const uint32_t* __restrict__ PA,
                          uint32_t* __restrict__ R8) {
    int idx = blockIdx.x * blockDim.x + threadIdx.x;   // 0 .. 8*HW_-1
    int w = idx % HW_;
    int g = idx / HW_;
    uint32_t h0a = 0, h12a = 0, h0b = 0, h12b = 0;
    const uint32_t* p = PA + (size_t)g * SLAB_PER_G * HW_ + w;
#pragma unroll 8
    for (int s = 0; s < SLAB_PER_G; ++s) {
        uint32_t v = p[(size_t)s * HW_];
        h0a  += v & 0xFFu;
        h12a += (v >> 8) & 0xFFu;
        h0b  += (v >> 16) & 0xFFu;
        h12b += v >> 24;
    }
    uint32_t* o = R8 + (size_t)g * NE_TOT;
    o[2 * w]     = h0a | (h12a << 16);
    o[2 * w + 1] = h0b | (h12b << 16);
}

// ---------- kB: ballot-scan tables + base counts (2 barriers) -------------
__global__ void k_tables_base(const uint32_t* __restrict__ R8,
                              const int* __restrict__ usn,
                              int* __restrict__ wtbl,
                              int* __restrict__ wne,
                              float* __restrict__ out_counts) {
    __shared__ int s_c[N_UNITS];
    __shared__ int wsum[8];
    int b = blockIdx.x;          // neighborhood id
    int u = threadIdx.x;         // 512 threads = 8 waves
    int h0 = 0, h3 = 0;
    if (u < N_UNITS) {
        int e = b * N_UNITS + u;
        // packed u16-field add: per-field totals << 65536, no cross-carry
        uint32_t tot = 0;
#pragma unroll
        for (int g = 0; g < RGROUPS; ++g) tot += R8[g * NE_TOT + e];
        h0 = (int)(tot & 0xFFFFu);
        h3 = h0 + (int)(tot >> 16);
        s_c[u] = h3;              // top0 + top1/top2 contributions
    }
    bool p = (u < N_UNITS) && (h0 > 0);
    unsigned long long m = __ballot(p);
    int lane = u & 63, wid = u >> 6;
    if (lane == 0) wsum[wid] = __popcll(m);
    int lp = __popcll(m & ((1ull << lane) - 1ull));
    __syncthreads();              // covers s_c and wsum
    int off = 0;
    for (int w2 = 0; w2 < wid; ++w2) off += wsum[w2];
    if (p) wtbl[b * N_UNITS + off + lp] = u;   // ascending unit order kept
    if (u == 0) {
        int tot = 0;
        for (int w2 = 0; w2 < 8; ++w2) tot += wsum[w2];
        wne[b] = tot;
    }
    if (u < N_UNITS && h3 > 0) {
        int2 nbr = ((const int2*)usn)[u];
        atomicAdd(&s_c[nbr.x], h3);
        atomicAdd(&s_c[nbr.y], h3);
    }
    __syncthreads();
    if (u < N_UNITS)
        out_counts[u * N_NEIGHB + b] = (float)s_c[u];
}

// ---------- k_main: barrier-free streaming + wave-local LDS transpose -----
// Each lane computes ONE spike's 10 candidates, packs them as 5 u32 (u16
// fields) into a per-wave 320-word LDS tile (stride-5 -> conflict-free).
// After lgkmcnt(0) (wave-lockstep: no block barrier needed), the wave
// re-reads transposed and stores fully-coalesced float4/float2 runs.
// Element map: u16 elem e in [0,640) lives in word e/2; read round k in
// {0,1}: lane L reads uint2 index L+64k = elems 256k+4L..+3 -> wo=256k+4L;
// round 2: word 256+L = elems 512+2L,513+2L -> wo=512+2L.
// ROUND-10: 512-thread blocks (8 waves), ~505-block grid -> ~16 waves/CU
// (round-7 counters: Occupancy 16.7%, VALU 9%, HBM 46% => latency-bound on
// thin occupancy; grid shape, not LDS, was the limiter).
__global__ __launch_bounds__(BSM, 4)
void k_main(const float* __restrict__ logliks,
            const int* __restrict__ top,
            const int* __restrict__ usn,
            const int* __restrict__ nbid,
            const int* __restrict__ wtbl,
            const int* __restrict__ wne,
            uint32_t* __restrict__ PD,
            float* __restrict__ out_cand,
            float* __restrict__ out_scores,
            int n, int chunk) {
    __shared__ uint32_t hist[EHW];                       // 25.6 KB
    __shared__ int   s_usn[N_UNITS * S];                 // 3.2 KB
    __shared__ float s_ll[N_UNITS];                      // 1.6 KB
    __shared__ int   s_ne[N_NEIGHB];                     // 0.25 KB
    __shared__ uint32_t xbuf[BSM / 64][320];             // 10.24 KB transpose tiles
    int tid = threadIdx.x;
    for (int k = tid; k < EHW; k += BSM) hist[k] = 0u;
    for (int k = tid; k < N_UNITS * S; k += BSM) s_usn[k] = usn[k];
    for (int k = tid; k < N_UNITS; k += BSM)     s_ll[k]  = logliks[k];
    for (int k = tid; k < N_NEIGHB; k += BSM)    s_ne[k]  = wne[k];
    __syncthreads();

    int lane = tid & 63, wid = tid >> 6;
    uint32_t* xb = xbuf[wid];

    // per-spike candidate build + dup-erase; vv gets the T final values
    auto do_spike = [&](int i, int nb, int t0v, int t1v, int t2v, int* vv) {
        int cand[T];
        cand[0] = t0v; cand[1] = t1v; cand[2] = t2v;
#pragma unroll
        for (int c = 0; c < C; ++c) {
            cand[C + 2 * c]     = s_usn[cand[c] * 2 + 0];
            cand[C + 2 * c + 1] = s_usn[cand[c] * 2 + 1];
        }
        int ne = s_ne[nb];
        if (ne > 0) {
            int t = explore_index(i, ne);
            int ex = wtbl[nb * N_UNITS + t];
            cand[T - 1] = ex;
            // explore tail-count (pre-dup), u8 field per nb
            atomicAdd(&hist[ex * 16 + (nb >> 2)], 1u << ((nb & 3) * 8));
        } else {
            cand[T - 1] = -1;
        }
#pragma unroll
        for (int jj = 0; jj < T; ++jj) {
            bool dup = false;
#pragma unroll
            for (int k = 0; k < jj; ++k) dup |= (cand[k] == cand[jj]);
            vv[jj] = dup ? -1 : cand[jj];
        }
    };

    int lo = blockIdx.x * chunk, hi = min(n, lo + chunk);
    for (int wbase = lo + wid * 64; wbase < hi; wbase += BSM) {
        if (wbase + 64 <= hi) {
            int i = wbase + lane;
            int nb = nbid[i];                    // wave: 256B contiguous
            const int* tp = top + 3 * (size_t)i; // wave: 768B contiguous
            int vv[T];
            do_spike(i, nb, tp[0], tp[1], tp[2], vv);
            // pack 10 u16 -> 5 u32; LDS stride-5 across lanes = conflict-free
#pragma unroll
            for (int k = 0; k < T / 2; ++k)
                xb[lane * 5 + k] = (uint32_t)(unsigned short)vv[2 * k]
                                 | ((uint32_t)(unsigned short)vv[2 * k + 1] << 16);
            // intra-wave cross-lane visibility: drain LDS writes (lockstep wave)
            asm volatile("s_waitcnt lgkmcnt(0)" ::: "memory");
            __builtin_amdgcn_sched_barrier(0);

            float* ocw = out_cand   + (size_t)wbase * T;
            float* osw = out_scores + (size_t)wbase * T;
            const uint2* xb2 = (const uint2*)xb;
            // rounds 0/1: elems [0,512): lane L round k -> elems 256k+4L..+3
#pragma unroll
            for (int k = 0; k < 2; ++k) {
                uint2 wv = xb2[lane + 64 * k];   // words 128k+2L, 128k+2L+1
                int v0 = (short)(wv.x & 0xFFFFu), v1 = (short)(wv.x >> 16);
                int v2 = (short)(wv.y & 0xFFFFu), v3 = (short)(wv.y >> 16);
                int wo = 4 * lane + 256 * k;
                *(float4*)(ocw + wo) =
                    make_float4((float)v0, (float)v1, (float)v2, (float)v3);
                *(float4*)(osw + wo) =
                    make_float4(v0 >= 0 ? s_ll[v0] : 0.0f,
                                v1 >= 0 ? s_ll[v1] : 0.0f,
                                v2 >= 0 ? s_ll[v2] : 0.0f,
                                v3 >= 0 ? s_ll[v3] : 0.0f);
            }
            // round 2 (partial): elems [512,640): word 256+L
            {
                uint32_t wv = xb[256 + lane];
                int v0 = (short)(wv & 0xFFFFu), v1 = (short)(wv >> 16);
                int wo = 512 + 2 * lane;
                *(float2*)(ocw + wo) = make_float2((float)v0, (float)v1);
                *(float2*)(osw + wo) =
                    make_float2(v0 >= 0 ? s_ll[v0] : 0.0f,
                                v1 >= 0 ? s_ll[v1] : 0.0f);
            }
            // stores consumed the LDS reads (compiler-waited); next-iter
            // ds_writes issue after, and the per-wave LDS pipe is in-order.
        } else {
            int i = wbase + lane;                // partial tail round (<64)
            if (i < hi) {
                int vv[T];
                do_spike(i, nbid[i], top[3 * i], top[3 * i + 1],
                         top[3 * i + 2], vv);
                for (int jj = 0; jj < T; ++jj) {
                    int v = vv[jj];
                    out_cand[(size_t)i * T + jj]   = (float)v;
                    out_scores[(size_t)i * T + jj] = (v >= 0) ? s_ll[v] : 0.0f;
                }
            }
        }
    }
    __syncthreads();        // all hist atomics complete
    uint32_t* Pb = PD + (size_t)blockIdx.x * EHW;
    for (int k = tid; k < EHW; k += BSM) Pb[k] = hist[k];
}

// ---------- kF: reduce u8-packed explore partials into out_counts ---------
// 200 blocks: 32 words x 8 slab-groups each.
__global__ void k_finalE(const uint32_t* __restrict__ PD,
                         float* __restrict__ out_counts, int nslab) {
    __shared__ uint32_t red_e[256], red_o[256];
    int tid = threadIdx.x;
    int wl = tid & 31, g = tid >> 5;            // 8 slab groups
    int w = blockIdx.x * 32 + wl;               // word index in [0, EHW)
    int per = (nslab + 7) >> 3;
    int s0 = g * per, s1 = min(nslab, s0 + per);
    uint32_t acc_e = 0, acc_o = 0;              // u16 lanes: fields 0/2, 1/3
    for (int s = s0; s < s1; ++s) {
        uint32_t v = PD[(size_t)s * EHW + w];
        acc_e += v & 0x00FF00FFu;
        acc_o += (v >> 8) & 0x00FF00FFu;
    }
    red_e[tid] = acc_e;
    red_o[tid] = acc_o;
    __syncthreads();
    if (g == 0) {
        // unpack BEFORE combining groups (avoid u16-lane carry)
        uint32_t c0 = 0, c1 = 0, c2 = 0, c3 = 0;
#pragma unroll
        for (int k = 0; k < 8; ++k) {
            uint32_t e = red_e[wl + 32 * k], o = red_o[wl + 32 * k];
            c0 += e & 0xFFFFu;  c2 += e >> 16;
            c1 += o & 0xFFFFu;  c3 += o >> 16;
        }
        int u = w >> 4, nb4 = (w & 15) * 4;
        float4* p = (float4*)(out_counts + u * N_NEIGHB + nb4);
        float4 v = *p;
        v.x += (float)c0;
        v.y += (float)c1;
        v.z += (float)c2;
        v.w += (float)c3;
        *p = v;
    }
}

extern "C" void kernel_launch(void* const* d_in, const int* in_sizes, int n_in,
                              void* d_out, int out_size, void* d_ws, size_t ws_size,
                              hipStream_t stream) {
    const float* logliks = (const float*)d_in[0];
    const int*   top     = (const int*)d_in[1];
    const int*   usn     = (const int*)d_in[2];
    const int*   nbid    = (const int*)d_in[3];

    int n = in_sizes[3];                                 // N_SPIKES
    int chunkA = ((n + NSLICE - 1) / NSLICE + 3) & ~3;   // mult of 4 (int4 path)
    // k_main chunk: multiple of 64 so every wave-round is full (n % 64 == 0)
    int chunkM = (((n + MBLK - 1) / MBLK) + 63) & ~63;   // 1984 at n=1e6
    int mb = (n + chunkM - 1) / chunkM;                  // 505 blocks (<= MBLK)

    float* out        = (float*)d_out;
    float* out_cand   = out;
    float* out_counts = out + (size_t)n * T;
    float* out_scores = out_counts + (size_t)N_UNITS * N_NEIGHB;

    // Scratch in d_ws (~27.1 MB used):
    int*      wtbl = (int*)d_ws;                         // [64][400]
    int*      wne  = wtbl + N_NEIGHB * N_UNITS;          // [64]
    uint32_t* R8   = (uint32_t*)(wne + 64);              // 8*25600 = 819.2 KB
    uint32_t* PA   = R8 + (size_t)RGROUPS * NE_TOT;      // 256*12800 = 13.1 MB
    uint32_t* PD   = PA + (size_t)NSLICE * HW_;          // <=512*6400 = 13.1 MB

    k_histA      <<<NSLICE, BSA, 0, stream>>>(top, nbid, PA, n, chunkA);
    k_reduceA    <<<(RGROUPS * HW_) / BS, BS, 0, stream>>>(PA, R8);
    k_tables_base<<<N_NEIGHB, 512, 0, stream>>>(R8, usn, wtbl, wne, out_counts);
    k_main       <<<mb, BSM, 0, stream>>>(logliks, top, usn, nbid, wtbl, wne,
                                          PD, out_cand, out_scores, n, chunkM);
    k_finalE     <<<EHW / 32, BS, 0, stream>>>(PD, out_counts, mb);
}

// Round 11
// 131.318 us; speedup vs baseline: 1.2136x; 1.0009x over previous
//
#include <hip/hip_runtime.h>
#include <stdint.h>

#define N_UNITS   400
#define N_NEIGHB  64
#define C         3
#define S         2
#define T         10      // C + C*S + E, E=1
#define NSLICE    256     // kA blocks / PA slabs
#define HW_       (N_NEIGHB * N_UNITS / 2)   // 12800 packed words (4 u8 fields each)
#define NE_TOT    (N_NEIGHB * N_UNITS)       // 25600 (nb,u) entries
#define RGROUPS   8
#define SLAB_PER_G (NSLICE / RGROUPS)        // 32
#define BS        256
#define BSM       1024                        // k_main block size (16 waves)
#define BSA       1024                        // kA block size
#define MBLK      512                         // max k_main blocks (PD slabs)
#define EHW       (N_UNITS * 16)              // 6400 u8x4-packed explore words

// ---------- JAX Threefry-2x32, key = (0, 1) (jax.random.key(1)) ----------
__device__ __forceinline__ uint32_t rotl32(uint32_t x, int d) {
    return (x << d) | (x >> (32 - d));
}

__device__ __forceinline__ void threefry_key01(uint32_t x0, uint32_t x1,
                                               uint32_t& o0, uint32_t& o1) {
    const uint32_t ks0 = 0u;
    const uint32_t ks1 = 1u;
    const uint32_t ks2 = 0x1BD11BDBu;  // 0x1BD11BDA ^ 0 ^ 1
    x0 += ks0; x1 += ks1;
#define TF_RND(r) { x0 += x1; x1 = rotl32(x1, r); x1 ^= x0; }
    TF_RND(13) TF_RND(15) TF_RND(26) TF_RND(6)
    x0 += ks1; x1 += ks2 + 1u;
    TF_RND(17) TF_RND(29) TF_RND(16) TF_RND(24)
    x0 += ks2; x1 += ks0 + 2u;
    TF_RND(13) TF_RND(15) TF_RND(26) TF_RND(6)
    x0 += ks0; x1 += ks1 + 3u;
    TF_RND(17) TF_RND(29) TF_RND(16) TF_RND(24)
    x0 += ks1; x1 += ks2 + 4u;
    TF_RND(13) TF_RND(15) TF_RND(26) TF_RND(6)
    x0 += ks2; x1 += ks0 + 5u;
#undef TF_RND
    o0 = x0; o1 = x1;
}

// jax_threefry_partitionable=True (default since jax 0.4.36):
// bits[i] = x0 ^ x1 of threefry2x32(key, (i >> 32, i & 0xffffffff)).
__device__ __forceinline__ int explore_index(int i, int ne) {
    uint32_t o0, o1;
    threefry_key01(0u, (uint32_t)i, o0, o1);
    uint32_t bits = o0 ^ o1;
    float u = __uint_as_float((bits >> 9) | 0x3F800000u) - 1.0f;
    int t = (int)floorf(u * (float)ne);
    return min(t, ne - 1);
}

// ---------- kA: single-pass full-64-nb partial histograms (u8 fields) -----
// entry e = nb*400+u; word = e>>1; lo/hi 16b half per e; within a half:
// bits 0-7 = h0 (top0 count), bits 8-15 = h12 (top1+top2 count).
// Per-slab counts are tiny (lambda ~0.3), so u8 cannot overflow.
__global__ void k_histA(const int* __restrict__ top,
                        const int* __restrict__ nbid,
                        uint32_t* __restrict__ PA, int n, int chunk) {
    __shared__ uint32_t hist[HW_];
    for (int k = threadIdx.x; k < HW_; k += blockDim.x) hist[k] = 0u;
    __syncthreads();
    int lo = blockIdx.x * chunk, hi = min(n, lo + chunk);
    const int4* top4 = (const int4*)top;
#define PROC(nb, t0, t1, t2) { \
    int b_ = (nb) * N_UNITS; \
    int e0 = b_ + (t0), e1 = b_ + (t1), e2 = b_ + (t2); \
    atomicAdd(&hist[e0 >> 1], 1u << ((e0 & 1) * 16)); \
    atomicAdd(&hist[e1 >> 1], 0x100u << ((e1 & 1) * 16)); \
    atomicAdd(&hist[e2 >> 1], 0x100u << ((e2 & 1) * 16)); }
    for (int i0 = lo + threadIdx.x * 4; i0 < hi; i0 += blockDim.x * 4) {
        if (i0 + 4 <= hi) {
            int4 nb4 = *(const int4*)(nbid + i0);
            int j = (i0 * 3) >> 2;
            int4 ta = top4[j], tb = top4[j + 1], tc = top4[j + 2];
            PROC(nb4.x, ta.x, ta.y, ta.z)
            PROC(nb4.y, ta.w, tb.x, tb.y)
            PROC(nb4.z, tb.z, tb.w, tc.x)
            PROC(nb4.w, tc.y, tc.z, tc.w)
        } else {
            for (int i = i0; i < hi; ++i)
                PROC(nbid[i], top[3 * i], top[3 * i + 1], top[3 * i + 2])
        }
    }
#undef PROC
    __syncthreads();
    uint32_t* Pb = PA + (size_t)blockIdx.x * HW_;
    for (int k = threadIdx.x; k < HW_; k += blockDim.x) Pb[k] = hist[k];
}

// ---------- kR: wide reduce of PA slabs into 8 packed partials ------------
// 400 blocks: full-chip spread of the 13.1 MB PA read (do NOT fuse into kB:
// 64-block version is latency-bound on 25% of CUs — round-4 regression).
__global__ void k_reduceA(const uint32_t* __restrict__ PA,
                          uint32_t* __restrict__ R8) {
    int idx = blockIdx.x * blockDim.x + threadIdx.x;   // 0 .. 8*HW_-1
    int w = idx % HW_;
    int g = idx / HW_;
    uint32_t h0a = 0, h12a = 0, h0b = 0, h12b = 0;
    const uint32_t* p = PA + (size_t)g * SLAB_PER_G * HW_ + w;
#pragma unroll 8
    for (int s = 0; s < SLAB_PER_G; ++s) {
        uint32_t v = p[(size_t)s * HW_];
        h0a  += v & 0xFFu;
        h12a += (v >> 8) & 0xFFu;
        h0b  += (v >> 16) & 0xFFu;
        h12b += v >> 24;
    }
    uint32_t* o = R8 + (size_t)g * NE_TOT;
    o[2 * w]     = h0a | (h12a << 16);
    o[2 * w + 1] = h0b | (h12b << 16);
}

// ---------- kB: ballot-scan tables + base counts (2 barriers) -------------
__global__ void k_tables_base(const uint32_t* __restrict__ R8,
                              const int* __restrict__ usn,
                              int* __restrict__ wtbl,
                              int* __restrict__ wne,
                              float* __restrict__ out_counts) {
    __shared__ int s_c[N_UNITS];
    __shared__ int wsum[8];
    int b = blockIdx.x;          // neighborhood id
    int u = threadIdx.x;         // 512 threads = 8 waves
    int h0 = 0, h3 = 0;
    if (u < N_UNITS) {
        int e = b * N_UNITS + u;
        // packed u16-field add: per-field totals << 65536, no cross-carry
        uint32_t tot = 0;
#pragma unroll
        for (int g = 0; g < RGROUPS; ++g) tot += R8[g * NE_TOT + e];
        h0 = (int)(tot & 0xFFFFu);
        h3 = h0 + (int)(tot >> 16);
        s_c[u] = h3;              // top0 + top1/top2 contributions
    }
    bool p = (u < N_UNITS) && (h0 > 0);
    unsigned long long m = __ballot(p);
    int lane = u & 63, wid = u >> 6;
    if (lane == 0) wsum[wid] = __popcll(m);
    int lp = __popcll(m & ((1ull << lane) - 1ull));
    __syncthreads();              // covers s_c and wsum
    int off = 0;
    for (int w2 = 0; w2 < wid; ++w2) off += wsum[w2];
    if (p) wtbl[b * N_UNITS + off + lp] = u;   // ascending unit order kept
    if (u == 0) {
        int tot = 0;
        for (int w2 = 0; w2 < 8; ++w2) tot += wsum[w2];
        wne[b] = tot;
    }
    if (u < N_UNITS && h3 > 0) {
        int2 nbr = ((const int2*)usn)[u];
        atomicAdd(&s_c[nbr.x], h3);
        atomicAdd(&s_c[nbr.y], h3);
    }
    __syncthreads();
    if (u < N_UNITS)
        out_counts[u * N_NEIGHB + b] = (float)s_c[u];
}

// ---------- k_main: barrier-free streaming + wave-local LDS transpose -----
// Each lane computes ONE spike's 10 candidates, packs them as 5 u32 (u16
// fields) into a per-wave 320-word LDS tile (stride-5 -> conflict-free).
// After lgkmcnt(0) (wave-lockstep: no block barrier needed), the wave
// re-reads transposed and stores fully-coalesced float4/float2 runs.
// Element map: u16 elem e in [0,640) lives in word e/2; read round k in
// {0,1}: lane L reads uint2 index L+64k = elems 256k+4L..+3 -> wo=256k+4L;
// round 2: word 256+L = elems 512+2L,513+2L -> wo=512+2L.
// ROUND-11: 1024-thread blocks (16 waves), 505-block grid, LDS 51.2 KB
// -> 2 blocks/CU x 16 waves = 32 waves/CU (HW max; round-10's 16 waves/CU
// confirmed the occupancy mechanism, this saturates it). launch_bounds
// (1024,8) pins VGPR <= 64 (measured 44 at round 7) so 8 waves/SIMD fit.
__global__ __launch_bounds__(BSM, 8)
void k_main(const float* __restrict__ logliks,
            const int* __restrict__ top,
            const int* __restrict__ usn,
            const int* __restrict__ nbid,
            const int* __restrict__ wtbl,
            const int* __restrict__ wne,
            uint32_t* __restrict__ PD,
            float* __restrict__ out_cand,
            float* __restrict__ out_scores,
            int n, int chunk) {
    __shared__ uint32_t hist[EHW];                       // 25.6 KB
    __shared__ int   s_usn[N_UNITS * S];                 // 3.2 KB
    __shared__ float s_ll[N_UNITS];                      // 1.6 KB
    __shared__ int   s_ne[N_NEIGHB];                     // 0.25 KB
    __shared__ uint32_t xbuf[BSM / 64][320];             // 20.5 KB transpose tiles
    int tid = threadIdx.x;
    for (int k = tid; k < EHW; k += BSM) hist[k] = 0u;
    for (int k = tid; k < N_UNITS * S; k += BSM) s_usn[k] = usn[k];
    for (int k = tid; k < N_UNITS; k += BSM)     s_ll[k]  = logliks[k];
    for (int k = tid; k < N_NEIGHB; k += BSM)    s_ne[k]  = wne[k];
    __syncthreads();

    int lane = tid & 63, wid = tid >> 6;
    uint32_t* xb = xbuf[wid];

    // per-spike candidate build + dup-erase; vv gets the T final values
    auto do_spike = [&](int i, int nb, int t0v, int t1v, int t2v, int* vv) {
        int cand[T];
        cand[0] = t0v; cand[1] = t1v; cand[2] = t2v;
#pragma unroll
        for (int c = 0; c < C; ++c) {
            cand[C + 2 * c]     = s_usn[cand[c] * 2 + 0];
            cand[C + 2 * c + 1] = s_usn[cand[c] * 2 + 1];
        }
        int ne = s_ne[nb];
        if (ne > 0) {
            int t = explore_index(i, ne);
            int ex = wtbl[nb * N_UNITS + t];
            cand[T - 1] = ex;
            // explore tail-count (pre-dup), u8 field per nb
            atomicAdd(&hist[ex * 16 + (nb >> 2)], 1u << ((nb & 3) * 8));
        } else {
            cand[T - 1] = -1;
        }
#pragma unroll
        for (int jj = 0; jj < T; ++jj) {
            bool dup = false;
#pragma unroll
            for (int k = 0; k < jj; ++k) dup |= (cand[k] == cand[jj]);
            vv[jj] = dup ? -1 : cand[jj];
        }
    };

    int lo = blockIdx.x * chunk, hi = min(n, lo + chunk);
    for (int wbase = lo + wid * 64; wbase < hi; wbase += BSM) {
        if (wbase + 64 <= hi) {
            int i = wbase + lane;
            int nb = nbid[i];                    // wave: 256B contiguous
            const int* tp = top + 3 * (size_t)i; // wave: 768B contiguous
            int vv[T];
            do_spike(i, nb, tp[0], tp[1], tp[2], vv);
            // pack 10 u16 -> 5 u32; LDS stride-5 across lanes = conflict-free
#pragma unroll
            for (int k = 0; k < T / 2; ++k)
                xb[lane * 5 + k] = (uint32_t)(unsigned short)vv[2 * k]
                                 | ((uint32_t)(unsigned short)vv[2 * k + 1] << 16);
            // intra-wave cross-lane visibility: drain LDS writes (lockstep wave)
            asm volatile("s_waitcnt lgkmcnt(0)" ::: "memory");
            __builtin_amdgcn_sched_barrier(0);

            float* ocw = out_cand   + (size_t)wbase * T;
            float* osw = out_scores + (size_t)wbase * T;
            const uint2* xb2 = (const uint2*)xb;
            // rounds 0/1: elems [0,512): lane L round k -> elems 256k+4L..+3
#pragma unroll
            for (int k = 0; k < 2; ++k) {
                uint2 wv = xb2[lane + 64 * k];   // words 128k+2L, 128k+2L+1
                int v0 = (short)(wv.x & 0xFFFFu), v1 = (short)(wv.x >> 16);
                int v2 = (short)(wv.y & 0xFFFFu), v3 = (short)(wv.y >> 16);
                int wo = 4 * lane + 256 * k;
                *(float4*)(ocw + wo) =
                    make_float4((float)v0, (float)v1, (float)v2, (float)v3);
                *(float4*)(osw + wo) =
                    make_float4(v0 >= 0 ? s_ll[v0] : 0.0f,
                                v1 >= 0 ? s_ll[v1] : 0.0f,
                                v2 >= 0 ? s_ll[v2] : 0.0f,
                                v3 >= 0 ? s_ll[v3] : 0.0f);
            }
            // round 2 (partial): elems [512,640): word 256+L
            {
                uint32_t wv = xb[256 + lane];
                int v0 = (short)(wv & 0xFFFFu), v1 = (short)(wv >> 16);
                int wo = 512 + 2 * lane;
                *(float2*)(ocw + wo) = make_float2((float)v0, (float)v1);
                *(float2*)(osw + wo) =
                    make_float2(v0 >= 0 ? s_ll[v0] : 0.0f,
                                v1 >= 0 ? s_ll[v1] : 0.0f);
            }
            // stores consumed the LDS reads (compiler-waited); next-iter
            // ds_writes issue after, and the per-wave LDS pipe is in-order.
        } else {
            int i = wbase + lane;                // partial tail round (<64)
            if (i < hi) {
                int vv[T];
                do_spike(i, nbid[i], top[3 * i], top[3 * i + 1],
                         top[3 * i + 2], vv);
                for (int jj = 0; jj < T; ++jj) {
                    int v = vv[jj];
                    out_cand[(size_t)i * T + jj]   = (float)v;
                    out_scores[(size_t)i * T + jj] = (v >= 0) ? s_ll[v] : 0.0f;
                }
            }
        }
    }
    __syncthreads();        // all hist atomics complete
    uint32_t* Pb = PD + (size_t)blockIdx.x * EHW;
    for (int k = tid; k < EHW; k += BSM) Pb[k] = hist[k];
}

// ---------- kF: reduce u8-packed explore partials into out_counts ---------
// 200 blocks: 32 words x 8 slab-groups each.
__global__ void k_finalE(const uint32_t* __restrict__ PD,
                         float* __restrict__ out_counts, int nslab) {
    __shared__ uint32_t red_e[256], red_o[256];
    int tid = threadIdx.x;
    int wl = tid & 31, g = tid >> 5;            // 8 slab groups
    int w = blockIdx.x * 32 + wl;               // word index in [0, EHW)
    int per = (nslab + 7) >> 3;
    int s0 = g * per, s1 = min(nslab, s0 + per);
    uint32_t acc_e = 0, acc_o = 0;              // u16 lanes: fields 0/2, 1/3
    for (int s = s0; s < s1; ++s) {
        uint32_t v = PD[(size_t)s * EHW + w];
        acc_e += v & 0x00FF00FFu;
        acc_o += (v >> 8) & 0x00FF00FFu;
    }
    red_e[tid] = acc_e;
    red_o[tid] = acc_o;
    __syncthreads();
    if (g == 0) {
        // unpack BEFORE combining groups (avoid u16-lane carry)
        uint32_t c0 = 0, c1 = 0, c2 = 0, c3 = 0;
#pragma unroll
        for (int k = 0; k < 8; ++k) {
            uint32_t e = red_e[wl + 32 * k], o = red_o[wl + 32 * k];
            c0 += e & 0xFFFFu;  c2 += e >> 16;
            c1 += o & 0xFFFFu;  c3 += o >> 16;
        }
        int u = w >> 4, nb4 = (w & 15) * 4;
        float4* p = (float4*)(out_counts + u * N_NEIGHB + nb4);
        float4 v = *p;
        v.x += (float)c0;
        v.y += (float)c1;
        v.z += (float)c2;
        v.w += (float)c3;
        *p = v;
    }
}

extern "C" void kernel_launch(void* const* d_in, const int* in_sizes, int n_in,
                              void* d_out, int out_size, void* d_ws, size_t ws_size,
                              hipStream_t stream) {
    const float* logliks = (const float*)d_in[0];
    const int*   top     = (const int*)d_in[1];
    const int*   usn     = (const int*)d_in[2];
    const int*   nbid    = (const int*)d_in[3];

    int n = in_sizes[3];                                 // N_SPIKES
    int chunkA = ((n + NSLICE - 1) / NSLICE + 3) & ~3;   // mult of 4 (int4 path)
    // k_main chunk: multiple of 64 so every wave-round is full (n % 64 == 0)
    int chunkM = (((n + MBLK - 1) / MBLK) + 63) & ~63;   // 1984 at n=1e6
    int mb = (n + chunkM - 1) / chunkM;                  // 505 blocks (<= MBLK)

    float* out        = (float*)d_out;
    float* out_cand   = out;
    float* out_counts = out + (size_t)n * T;
    float* out_scores = out_counts + (size_t)N_UNITS * N_NEIGHB;

    // Scratch in d_ws (~27.1 MB used):
    int*      wtbl = (int*)d_ws;                         // [64][400]
    int*      wne  = wtbl + N_NEIGHB * N_UNITS;          // [64]
    uint32_t* R8   = (uint32_t*)(wne + 64);              // 8*25600 = 819.2 KB
    uint32_t* PA   = R8 + (size_t)RGROUPS * NE_TOT;      // 256*12800 = 13.1 MB
    uint32_t* PD   = PA + (size_t)NSLICE * HW_;          // <=512*6400 = 13.1 MB

    k_histA      <<<NSLICE, BSA, 0, stream>>>(top, nbid, PA, n, chunkA);
    k_reduceA    <<<(RGROUPS * HW_) / BS, BS, 0, stream>>>(PA, R8);
    k_tables_base<<<N_NEIGHB, 512, 0, stream>>>(R8, usn, wtbl, wne, out_counts);
    k_main       <<<mb, BSM, 0, stream>>>(logliks, top, usn, nbid, wtbl, wne,
                                          PD, out_cand, out_scores, n, chunkM);
    k_finalE     <<<EHW / 32, BS, 0, stream>>>(PD, out_counts, mb);
}

// Round 12
// 126.041 us; speedup vs baseline: 1.2644x; 1.0419x over previous
//
#include <hip/hip_runtime.h>
#include <stdint.h>

#define N_UNITS   400
#define N_NEIGHB  64
#define C         3
#define S         2
#define T         10      // C + C*S + E, E=1
#define NSLICE    256     // kA blocks / PA slabs
#define HW_       (N_NEIGHB * N_UNITS / 2)   // 12800 packed words (4 u8 fields each)
#define NE_TOT    (N_NEIGHB * N_UNITS)       // 25600 (nb,u) entries
#define RGROUPS   8
#define SLAB_PER_G (NSLICE / RGROUPS)        // 32
#define BS        256
#define BSM       1024                        // k_main block size (16 waves)
#define BSA       1024                        // kA block size
#define MBLK      256                         // max k_main blocks (PD slabs)
#define EHW       (N_UNITS * 16)              // 6400 u8x4-packed explore words

// ---------- JAX Threefry-2x32, key = (0, 1) (jax.random.key(1)) ----------
__device__ __forceinline__ uint32_t rotl32(uint32_t x, int d) {
    return (x << d) | (x >> (32 - d));
}

__device__ __forceinline__ void threefry_key01(uint32_t x0, uint32_t x1,
                                               uint32_t& o0, uint32_t& o1) {
    const uint32_t ks0 = 0u;
    const uint32_t ks1 = 1u;
    const uint32_t ks2 = 0x1BD11BDBu;  // 0x1BD11BDA ^ 0 ^ 1
    x0 += ks0; x1 += ks1;
#define TF_RND(r) { x0 += x1; x1 = rotl32(x1, r); x1 ^= x0; }
    TF_RND(13) TF_RND(15) TF_RND(26) TF_RND(6)
    x0 += ks1; x1 += ks2 + 1u;
    TF_RND(17) TF_RND(29) TF_RND(16) TF_RND(24)
    x0 += ks2; x1 += ks0 + 2u;
    TF_RND(13) TF_RND(15) TF_RND(26) TF_RND(6)
    x0 += ks0; x1 += ks1 + 3u;
    TF_RND(17) TF_RND(29) TF_RND(16) TF_RND(24)
    x0 += ks1; x1 += ks2 + 4u;
    TF_RND(13) TF_RND(15) TF_RND(26) TF_RND(6)
    x0 += ks2; x1 += ks0 + 5u;
#undef TF_RND
    o0 = x0; o1 = x1;
}

// jax_threefry_partitionable=True (default since jax 0.4.36):
// bits[i] = x0 ^ x1 of threefry2x32(key, (i >> 32, i & 0xffffffff)).
__device__ __forceinline__ int explore_index(int i, int ne) {
    uint32_t o0, o1;
    threefry_key01(0u, (uint32_t)i, o0, o1);
    uint32_t bits = o0 ^ o1;
    float u = __uint_as_float((bits >> 9) | 0x3F800000u) - 1.0f;
    int t = (int)floorf(u * (float)ne);
    return min(t, ne - 1);
}

// ---------- kA: single-pass full-64-nb partial histograms (u8 fields) -----
// entry e = nb*400+u; word = e>>1; lo/hi 16b half per e; within a half:
// bits 0-7 = h0 (top0 count), bits 8-15 = h12 (top1+top2 count).
// Per-slab counts are tiny (lambda ~0.3), so u8 cannot overflow.
__global__ void k_histA(const int* __restrict__ top,
                        const int* __restrict__ nbid,
                        uint32_t* __restrict__ PA, int n, int chunk) {
    __shared__ uint32_t hist[HW_];
    for (int k = threadIdx.x; k < HW_; k += blockDim.x) hist[k] = 0u;
    __syncthreads();
    int lo = blockIdx.x * chunk, hi = min(n, lo + chunk);
    const int4* top4 = (const int4*)top;
#define PROC(nb, t0, t1, t2) { \
    int b_ = (nb) * N_UNITS; \
    int e0 = b_ + (t0), e1 = b_ + (t1), e2 = b_ + (t2); \
    atomicAdd(&hist[e0 >> 1], 1u << ((e0 & 1) * 16)); \
    atomicAdd(&hist[e1 >> 1], 0x100u << ((e1 & 1) * 16)); \
    atomicAdd(&hist[e2 >> 1], 0x100u << ((e2 & 1) * 16)); }
    for (int i0 = lo + threadIdx.x * 4; i0 < hi; i0 += blockDim.x * 4) {
        if (i0 + 4 <= hi) {
            int4 nb4 = *(const int4*)(nbid + i0);
            int j = (i0 * 3) >> 2;
            int4 ta = top4[j], tb = top4[j + 1], tc = top4[j + 2];
            PROC(nb4.x, ta.x, ta.y, ta.z)
            PROC(nb4.y, ta.w, tb.x, tb.y)
            PROC(nb4.z, tb.z, tb.w, tc.x)
            PROC(nb4.w, tc.y, tc.z, tc.w)
        } else {
            for (int i = i0; i < hi; ++i)
                PROC(nbid[i], top[3 * i], top[3 * i + 1], top[3 * i + 2])
        }
    }
#undef PROC
    __syncthreads();
    uint32_t* Pb = PA + (size_t)blockIdx.x * HW_;
    for (int k = threadIdx.x; k < HW_; k += blockDim.x) Pb[k] = hist[k];
}

// ---------- kR: wide reduce of PA slabs into 8 packed partials ------------
// 400 blocks: full-chip spread of the 13.1 MB PA read (do NOT fuse into kB:
// 64-block version is latency-bound on 25% of CUs — round-4 regression).
__global__ void k_reduceA(const uint32_t* __restrict__ PA,
                          uint32_t* __restrict__ R8) {
    int idx = blockIdx.x * blockDim.x + threadIdx.x;   // 0 .. 8*HW_-1
    int w = idx % HW_;
    int g = idx / HW_;
    uint32_t h0a = 0, h12a = 0, h0b = 0, h12b = 0;
    const uint32_t* p = PA + (size_t)g * SLAB_PER_G * HW_ + w;
#pragma unroll 8
    for (int s = 0; s < SLAB_PER_G; ++s) {
        uint32_t v = p[(size_t)s * HW_];
        h0a  += v & 0xFFu;
        h12a += (v >> 8) & 0xFFu;
        h0b  += (v >> 16) & 0xFFu;
        h12b += v >> 24;
    }
    uint32_t* o = R8 + (size_t)g * NE_TOT;
    o[2 * w]     = h0a | (h12a << 16);
    o[2 * w + 1] = h0b | (h12b << 16);
}

// ---------- kB: ballot-scan tables + base counts (2 barriers) -------------
__global__ void k_tables_base(const uint32_t* __restrict__ R8,
                              const int* __restrict__ usn,
                              int* __restrict__ wtbl,
                              int* __restrict__ wne,
                              float* __restrict__ out_counts) {
    __shared__ int s_c[N_UNITS];
    __shared__ int wsum[8];
    int b = blockIdx.x;          // neighborhood id
    int u = threadIdx.x;         // 512 threads = 8 waves
    int h0 = 0, h3 = 0;
    if (u < N_UNITS) {
        int e = b * N_UNITS + u;
        // packed u16-field add: per-field totals << 65536, no cross-carry
        uint32_t tot = 0;
#pragma unroll
        for (int g = 0; g < RGROUPS; ++g) tot += R8[g * NE_TOT + e];
        h0 = (int)(tot & 0xFFFFu);
        h3 = h0 + (int)(tot >> 16);
        s_c[u] = h3;              // top0 + top1/top2 contributions
    }
    bool p = (u < N_UNITS) && (h0 > 0);
    unsigned long long m = __ballot(p);
    int lane = u & 63, wid = u >> 6;
    if (lane == 0) wsum[wid] = __popcll(m);
    int lp = __popcll(m & ((1ull << lane) - 1ull));
    __syncthreads();              // covers s_c and wsum
    int off = 0;
    for (int w2 = 0; w2 < wid; ++w2) off += wsum[w2];
    if (p) wtbl[b * N_UNITS + off + lp] = u;   // ascending unit order kept
    if (u == 0) {
        int tot = 0;
        for (int w2 = 0; w2 < 8; ++w2) tot += wsum[w2];
        wne[b] = tot;
    }
    if (u < N_UNITS && h3 > 0) {
        int2 nbr = ((const int2*)usn)[u];
        atomicAdd(&s_c[nbr.x], h3);
        atomicAdd(&s_c[nbr.y], h3);
    }
    __syncthreads();
    if (u < N_UNITS)
        out_counts[u * N_NEIGHB + b] = (float)s_c[u];
}

// ---------- k_main: barrier-free streaming + wave-local LDS transpose -----
// Each lane computes ONE spike's 10 candidates, packs them as 5 u32 (u16
// fields) into a per-wave 320-word LDS tile (stride-5 -> conflict-free).
// After lgkmcnt(0) (wave-lockstep: no block barrier needed), the wave
// re-reads transposed and stores fully-coalesced float4/float2 runs.
// Element map: u16 elem e in [0,640) lives in word e/2; read round k in
// {0,1}: lane L reads uint2 index L+64k = elems 256k+4L..+3 -> wo=256k+4L;
// round 2: word 256+L = elems 512+2L,513+2L -> wo=512+2L.
// ROUND-12: 253 blocks x 1024 threads = 1 block/CU x 16 waves — R10==R11
// proved 16 waves/CU saturates latency-hiding, so halve the PD slab count
// (13.1 -> 6.5 MB partials traffic) at equal occupancy.
__global__ __launch_bounds__(BSM, 8)
void k_main(const float* __restrict__ logliks,
            const int* __restrict__ top,
            const int* __restrict__ usn,
            const int* __restrict__ nbid,
            const int* __restrict__ wtbl,
            const int* __restrict__ wne,
            uint32_t* __restrict__ PD,
            float* __restrict__ out_cand,
            float* __restrict__ out_scores,
            int n, int chunk) {
    __shared__ uint32_t hist[EHW];                       // 25.6 KB
    __shared__ int   s_usn[N_UNITS * S];                 // 3.2 KB
    __shared__ float s_ll[N_UNITS];                      // 1.6 KB
    __shared__ int   s_ne[N_NEIGHB];                     // 0.25 KB
    __shared__ uint32_t xbuf[BSM / 64][320];             // 20.5 KB transpose tiles
    int tid = threadIdx.x;
    for (int k = tid; k < EHW; k += BSM) hist[k] = 0u;
    for (int k = tid; k < N_UNITS * S; k += BSM) s_usn[k] = usn[k];
    for (int k = tid; k < N_UNITS; k += BSM)     s_ll[k]  = logliks[k];
    for (int k = tid; k < N_NEIGHB; k += BSM)    s_ne[k]  = wne[k];
    __syncthreads();

    int lane = tid & 63, wid = tid >> 6;
    uint32_t* xb = xbuf[wid];

    // per-spike candidate build + dup-erase; vv gets the T final values
    auto do_spike = [&](int i, int nb, int t0v, int t1v, int t2v, int* vv) {
        int cand[T];
        cand[0] = t0v; cand[1] = t1v; cand[2] = t2v;
#pragma unroll
        for (int c = 0; c < C; ++c) {
            cand[C + 2 * c]     = s_usn[cand[c] * 2 + 0];
            cand[C + 2 * c + 1] = s_usn[cand[c] * 2 + 1];
        }
        int ne = s_ne[nb];
        if (ne > 0) {
            int t = explore_index(i, ne);
            int ex = wtbl[nb * N_UNITS + t];
            cand[T - 1] = ex;
            // explore tail-count (pre-dup), u8 field per nb
            atomicAdd(&hist[ex * 16 + (nb >> 2)], 1u << ((nb & 3) * 8));
        } else {
            cand[T - 1] = -1;
        }
#pragma unroll
        for (int jj = 0; jj < T; ++jj) {
            bool dup = false;
#pragma unroll
            for (int k = 0; k < jj; ++k) dup |= (cand[k] == cand[jj]);
            vv[jj] = dup ? -1 : cand[jj];
        }
    };

    int lo = blockIdx.x * chunk, hi = min(n, lo + chunk);
    for (int wbase = lo + wid * 64; wbase < hi; wbase += BSM) {
        if (wbase + 64 <= hi) {
            int i = wbase + lane;
            int nb = nbid[i];                    // wave: 256B contiguous
            const int* tp = top + 3 * (size_t)i; // wave: 768B contiguous
            int vv[T];
            do_spike(i, nb, tp[0], tp[1], tp[2], vv);
            // pack 10 u16 -> 5 u32; LDS stride-5 across lanes = conflict-free
#pragma unroll
            for (int k = 0; k < T / 2; ++k)
                xb[lane * 5 + k] = (uint32_t)(unsigned short)vv[2 * k]
                                 | ((uint32_t)(unsigned short)vv[2 * k + 1] << 16);
            // intra-wave cross-lane visibility: drain LDS writes (lockstep wave)
            asm volatile("s_waitcnt lgkmcnt(0)" ::: "memory");
            __builtin_amdgcn_sched_barrier(0);

            float* ocw = out_cand   + (size_t)wbase * T;
            float* osw = out_scores + (size_t)wbase * T;
            const uint2* xb2 = (const uint2*)xb;
            // rounds 0/1: elems [0,512): lane L round k -> elems 256k+4L..+3
#pragma unroll
            for (int k = 0; k < 2; ++k) {
                uint2 wv = xb2[lane + 64 * k];   // words 128k+2L, 128k+2L+1
                int v0 = (short)(wv.x & 0xFFFFu), v1 = (short)(wv.x >> 16);
                int v2 = (short)(wv.y & 0xFFFFu), v3 = (short)(wv.y >> 16);
                int wo = 4 * lane + 256 * k;
                *(float4*)(ocw + wo) =
                    make_float4((float)v0, (float)v1, (float)v2, (float)v3);
                *(float4*)(osw + wo) =
                    make_float4(v0 >= 0 ? s_ll[v0] : 0.0f,
                                v1 >= 0 ? s_ll[v1] : 0.0f,
                                v2 >= 0 ? s_ll[v2] : 0.0f,
                                v3 >= 0 ? s_ll[v3] : 0.0f);
            }
            // round 2 (partial): elems [512,640): word 256+L
            {
                uint32_t wv = xb[256 + lane];
                int v0 = (short)(wv & 0xFFFFu), v1 = (short)(wv >> 16);
                int wo = 512 + 2 * lane;
                *(float2*)(ocw + wo) = make_float2((float)v0, (float)v1);
                *(float2*)(osw + wo) =
                    make_float2(v0 >= 0 ? s_ll[v0] : 0.0f,
                                v1 >= 0 ? s_ll[v1] : 0.0f);
            }
            // stores consumed the LDS reads (compiler-waited); next-iter
            // ds_writes issue after, and the per-wave LDS pipe is in-order.
        } else {
            int i = wbase + lane;                // partial tail round (<64)
            if (i < hi) {
                int vv[T];
                do_spike(i, nbid[i], top[3 * i], top[3 * i + 1],
                         top[3 * i + 2], vv);
                for (int jj = 0; jj < T; ++jj) {
                    int v = vv[jj];
                    out_cand[(size_t)i * T + jj]   = (float)v;
                    out_scores[(size_t)i * T + jj] = (v >= 0) ? s_ll[v] : 0.0f;
                }
            }
        }
    }
    __syncthreads();        // all hist atomics complete
    uint32_t* Pb = PD + (size_t)blockIdx.x * EHW;
    for (int k = tid; k < EHW; k += BSM) Pb[k] = hist[k];
}

// ---------- kF: reduce u8-packed explore partials into out_counts ---------
// 200 blocks: 32 words x 8 slab-groups each.
__global__ void k_finalE(const uint32_t* __restrict__ PD,
                         float* __restrict__ out_counts, int nslab) {
    __shared__ uint32_t red_e[256], red_o[256];
    int tid = threadIdx.x;
    int wl = tid & 31, g = tid >> 5;            // 8 slab groups
    int w = blockIdx.x * 32 + wl;               // word index in [0, EHW)
    int per = (nslab + 7) >> 3;
    int s0 = g * per, s1 = min(nslab, s0 + per);
    uint32_t acc_e = 0, acc_o = 0;              // u16 lanes: fields 0/2, 1/3
    for (int s = s0; s < s1; ++s) {
        uint32_t v = PD[(size_t)s * EHW + w];
        acc_e += v & 0x00FF00FFu;
        acc_o += (v >> 8) & 0x00FF00FFu;
    }
    red_e[tid] = acc_e;
    red_o[tid] = acc_o;
    __syncthreads();
    if (g == 0) {
        // unpack BEFORE combining groups (avoid u16-lane carry)
        uint32_t c0 = 0, c1 = 0, c2 = 0, c3 = 0;
#pragma unroll
        for (int k = 0; k < 8; ++k) {
            uint32_t e = red_e[wl + 32 * k], o = red_o[wl + 32 * k];
            c0 += e & 0xFFFFu;  c2 += e >> 16;
            c1 += o & 0xFFFFu;  c3 += o >> 16;
        }
        int u = w >> 4, nb4 = (w & 15) * 4;
        float4* p = (float4*)(out_counts + u * N_NEIGHB + nb4);
        float4 v = *p;
        v.x += (float)c0;
        v.y += (float)c1;
        v.z += (float)c2;
        v.w += (float)c3;
        *p = v;
    }
}

extern "C" void kernel_launch(void* const* d_in, const int* in_sizes, int n_in,
                              void* d_out, int out_size, void* d_ws, size_t ws_size,
                              hipStream_t stream) {
    const float* logliks = (const float*)d_in[0];
    const int*   top     = (const int*)d_in[1];
    const int*   usn     = (const int*)d_in[2];
    const int*   nbid    = (const int*)d_in[3];

    int n = in_sizes[3];                                 // N_SPIKES
    int chunkA = ((n + NSLICE - 1) / NSLICE + 3) & ~3;   // mult of 4 (int4 path)
    // k_main chunk: multiple of 64 so every wave-round is full (n % 64 == 0)
    int chunkM = (((n + MBLK - 1) / MBLK) + 63) & ~63;   // 3968 at n=1e6
    int mb = (n + chunkM - 1) / chunkM;                  // 253 blocks

    float* out        = (float*)d_out;
    float* out_cand   = out;
    float* out_counts = out + (size_t)n * T;
    float* out_scores = out_counts + (size_t)N_UNITS * N_NEIGHB;

    // Scratch in d_ws (~20.5 MB used):
    int*      wtbl = (int*)d_ws;                         // [64][400]
    int*      wne  = wtbl + N_NEIGHB * N_UNITS;          // [64]
    uint32_t* R8   = (uint32_t*)(wne + 64);              // 8*25600 = 819.2 KB
    uint32_t* PA   = R8 + (size_t)RGROUPS * NE_TOT;      // 256*12800 = 13.1 MB
    uint32_t* PD   = PA + (size_t)NSLICE * HW_;          // <=256*6400 = 6.6 MB

    k_histA      <<<NSLICE, BSA, 0, stream>>>(top, nbid, PA, n, chunkA);
    k_reduceA    <<<(RGROUPS * HW_) / BS, BS, 0, stream>>>(PA, R8);
    k_tables_base<<<N_NEIGHB, 512, 0, stream>>>(R8, usn, wtbl, wne, out_counts);
    k_main       <<<mb, BSM, 0, stream>>>(logliks, top, usn, nbid, wtbl, wne,
                                          PD, out_cand, out_scores, n, chunkM);
    k_finalE     <<<EHW / 32, BS, 0, stream>>>(PD, out_counts, mb);
}